// Round 11
// baseline (206.788 us; speedup 1.0000x reference)
//
#include <hip/hip_runtime.h>
#include <hip/hip_cooperative_groups.h>

namespace cg = cooperative_groups;

// AugmentShallow, round 11: single cooperative kernel (R4 math verbatim).
//
// Evidence: per-dispatch fixed cost ~20us dominates (R3 3-disp=106 vs R4
// 2-disp=77 for identical math; all per-CU throughput models say work=~35us).
// So: ONE dispatch. Phase 1 = R4 k_mlp (t = MLP(x), 2x64-pt chunks/block);
// grid.sync(); phase 2 = R4 k_out2 (gather-mean -> LDS -> W2 GEMM, 128 pts).
// Fallback to the two-kernel R4 pipeline if cooperative launch is rejected.
//
// ws: [0,16Mi) t f16 [65536][128].

typedef __attribute__((ext_vector_type(8))) _Float16 h8;
typedef __attribute__((ext_vector_type(4))) _Float16 h4;
typedef __attribute__((ext_vector_type(4))) float    f4;

#define MFMA_H __builtin_amdgcn_mfma_f32_16x16x32_f16

#define LO_SCALE_INV 2.44140625e-4f   // 2^-12

__device__ __forceinline__ void splitW8(const float* __restrict__ p, h8& hi, h8& lo) {
    const float4 a = *(const float4*)p;
    const float4 b = *(const float4*)(p + 4);
    const float v[8] = {a.x, a.y, a.z, a.w, b.x, b.y, b.z, b.w};
#pragma unroll
    for (int j = 0; j < 8; ++j) {
        const _Float16 h = (_Float16)v[j];
        hi[j] = h;
        lo[j] = (_Float16)((v[j] - (float)h) * 4096.f);
    }
}

// ---------------------------------------------------------------------------
// Phase 1 (R4 k_mlp body, 2 chunks of 64 pts): t[b,j] = MLP(x[b,j]).
// hA/hB are 64x128 f16 LDS planes (16 KiB each).
// ---------------------------------------------------------------------------
__device__ __forceinline__ void mlp_phase(
    int bid, int tid, _Float16* __restrict__ hA, _Float16* __restrict__ hB,
    const float* __restrict__ x,
    const float* __restrict__ W1, const float* __restrict__ b1,
    const float* __restrict__ Wc0, const float* __restrict__ bc0,
    const float* __restrict__ Wc1, const float* __restrict__ bc1,
    _Float16* __restrict__ t)
{
    const int lane = tid & 63;
    const int w  = tid >> 6;
    const int fr = lane & 15;
    const int g  = lane >> 4;
    const int ocb = w * 32;

#pragma unroll 1
    for (int qc = 0; qc < 2; ++qc) {
        const int lb1 = (bid & 7) * 128 + (bid >> 3) * 2 + qc;  // batch = bid&7
        const long pblk = (long)lb1 * 64;

        // ---- layer 1 (VALU, K=3, no relu): thread = (pt, 32-ch quarter) ----
        {
            const int pt  = tid >> 2;
            const int q4  = tid & 3;
            const int ch0 = q4 * 32;
            const float* xp = x + (pblk + pt) * 3;
            const float x0 = xp[0], x1 = xp[1], x2 = xp[2];
            const int p7 = pt & 7;
#pragma unroll
            for (int q = 0; q < 4; ++q) {
                h8 hv;
#pragma unroll
                for (int j = 0; j < 8; ++j) {
                    const int c = ch0 + q * 8 + j;
                    float v = b1[c];
                    v = fmaf(W1[c * 3 + 0], x0, v);
                    v = fmaf(W1[c * 3 + 1], x1, v);
                    v = fmaf(W1[c * 3 + 2], x2, v);
                    hv[j] = (_Float16)v;
                }
                const int chunk = q4 * 4 + q;
                *(h8*)&hA[pt * 128 + ((chunk ^ p7) << 3)] = hv;
            }
        }
        __syncthreads();

#pragma unroll 1
        for (int layer = 0; layer < 2; ++layer) {
            const float* W  = layer ? Wc1 : Wc0;
            const float* bp = layer ? bc1 : bc0;

            h8 Ah[2][4], Al[2][4];
#pragma unroll
            for (int T = 0; T < 2; ++T)
#pragma unroll
                for (int c = 0; c < 4; ++c)
                    splitW8(W + (long)(ocb + T * 16 + fr) * 128 + c * 32 + g * 8,
                            Ah[T][c], Al[T][c]);

            f4 bias[2];
#pragma unroll
            for (int T = 0; T < 2; ++T) {
                const float4 bv = *(const float4*)(bp + ocb + T * 16 + g * 4);
                bias[T] = (f4){bv.x, bv.y, bv.z, bv.w};
            }

            const _Float16* hin = layer ? hB : hA;
            const f4 zf = {0.f, 0.f, 0.f, 0.f};

#pragma unroll 2
            for (int p = 0; p < 4; ++p) {
                const int pt = p * 16 + fr;
                const int p7 = pt & 7;
                h8 B[4];
#pragma unroll
                for (int c = 0; c < 4; ++c)
                    B[c] = *(const h8*)&hin[pt * 128 + (((4 * c + g) ^ p7) << 3)];

                f4 ahi[2] = {bias[0], bias[1]};
                f4 alo[2] = {zf, zf};
#pragma unroll
                for (int c = 0; c < 4; ++c) {
#pragma unroll
                    for (int T = 0; T < 2; ++T) {
                        ahi[T] = MFMA_H(Ah[T][c], B[c], ahi[T], 0, 0, 0);
                        alo[T] = MFMA_H(Al[T][c], B[c], alo[T], 0, 0, 0);
                    }
                }
#pragma unroll
                for (int T = 0; T < 2; ++T) {
                    const int ocoff = ocb + T * 16 + g * 4;
                    h4 o;
#pragma unroll
                    for (int r = 0; r < 4; ++r)
                        o[r] = (_Float16)fmaxf(fmaf(alo[T][r], LO_SCALE_INV, ahi[T][r]), 0.f);
                    if (layer == 0) {
                        const int sidx = pt * 128 + (((ocoff >> 3) ^ p7) << 3) + (ocoff & 7);
                        *(h4*)&hB[sidx] = o;
                    } else {
                        *(h4*)&t[(pblk + pt) * 128 + ocoff] = o;
                    }
                }
            }
            if (layer == 0) __syncthreads();
        }
        // chunk qc+1's layer-1 writes hA (disjoint from this chunk's hB reads);
        // its post-layer-1 barrier orders the hB reuse. No extra barrier needed.
    }
}

// ---------------------------------------------------------------------------
// Phase 2 (R4 k_out2 body): gather-mean -> LDS -> out = W2 m + b2.
// mS is 128x128 f16 LDS (32 KiB). 128 pts per block.
// ---------------------------------------------------------------------------
__device__ __forceinline__ void out_phase(
    int bid, int tid, _Float16* __restrict__ mS,
    const int* __restrict__ knn,
    const _Float16* __restrict__ t,
    const float* __restrict__ W2, const float* __restrict__ b2,
    float* __restrict__ out)
{
    const int lb  = (bid & 7) * 64 + (bid >> 3);    // batch = lb>>6 = bid&7
    const long pbase = (long)lb * 128;
    const long bbase = (long)(bid & 7) * 8192;      // batch row base in t

    // ---- gather-mean into LDS: 4 passes x 32 pts; thread=(pt, 8-ch oct) ----
    {
        const int oct = tid & 7;
        const int o8  = oct * 8;
#pragma unroll 1
        for (int pass = 0; pass < 4; ++pass) {
            const int ptl = pass * 32 + (tid >> 3);
            const int* ip = knn + (pbase + ptl) * 12;
            int idx[12];
            *(int4*)&idx[0] = *(const int4*)(ip + 0);
            *(int4*)&idx[4] = *(const int4*)(ip + 4);
            *(int4*)&idx[8] = *(const int4*)(ip + 8);

            float acc[16];
#pragma unroll
            for (int c = 0; c < 16; ++c) acc[c] = 0.f;
#pragma unroll 4
            for (int k = 0; k < 12; ++k) {
                const _Float16* tp = t + (bbase + idx[k]) * 128;
                const h8 va = *(const h8*)(tp + o8);
                const h8 vb = *(const h8*)(tp + 64 + o8);
#pragma unroll
                for (int j = 0; j < 8; ++j) acc[j] += (float)va[j];
#pragma unroll
                for (int j = 0; j < 8; ++j) acc[8 + j] += (float)vb[j];
            }
            h8 oa, ob;
#pragma unroll
            for (int j = 0; j < 8; ++j) {
                oa[j] = (_Float16)(acc[j] * (1.f / 12.f));
                ob[j] = (_Float16)(acc[8 + j] * (1.f / 12.f));
            }
            const int p7 = ptl & 7;
            *(h8*)&mS[ptl * 128 + ((oct ^ p7) << 3)]       = oa;
            *(h8*)&mS[ptl * 128 + (((oct + 8) ^ p7) << 3)] = ob;
        }
    }
    __syncthreads();

    // ---- GEMM: out = W2 m + b2, two 128-oc halves, plain stores ----
    const int lane = tid & 63;
    const int w  = tid >> 6;
    const int fr = lane & 15;
    const int g  = lane >> 4;
    const f4 zf = {0.f, 0.f, 0.f, 0.f};

#pragma unroll 1
    for (int half = 0; half < 2; ++half) {
        const int ocb = half * 128 + w * 32;

        h8 Ah[2][4], Al[2][4];
#pragma unroll
        for (int T = 0; T < 2; ++T)
#pragma unroll
            for (int c = 0; c < 4; ++c)
                splitW8(W2 + (long)(ocb + T * 16 + fr) * 128 + c * 32 + g * 8,
                        Ah[T][c], Al[T][c]);

        f4 bias[2];
#pragma unroll
        for (int T = 0; T < 2; ++T) {
            const float4 bv = *(const float4*)(b2 + ocb + T * 16 + g * 4);
            bias[T] = (f4){bv.x, bv.y, bv.z, bv.w};
        }

#pragma unroll 2
        for (int p = 0; p < 8; ++p) {
            const int ptl = p * 16 + fr;
            const int p7  = ptl & 7;
            h8 B[4];
#pragma unroll
            for (int c = 0; c < 4; ++c)
                B[c] = *(const h8*)&mS[ptl * 128 + (((4 * c + g) ^ p7) << 3)];

            f4 ahi[2] = {bias[0], bias[1]};
            f4 alo[2] = {zf, zf};
#pragma unroll
            for (int c = 0; c < 4; ++c)
#pragma unroll
                for (int T = 0; T < 2; ++T) {
                    ahi[T] = MFMA_H(Ah[T][c], B[c], ahi[T], 0, 0, 0);
                    alo[T] = MFMA_H(Al[T][c], B[c], alo[T], 0, 0, 0);
                }
#pragma unroll
            for (int T = 0; T < 2; ++T) {
                float4 o;
                o.x = fmaf(alo[T][0], LO_SCALE_INV, ahi[T][0]);
                o.y = fmaf(alo[T][1], LO_SCALE_INV, ahi[T][1]);
                o.z = fmaf(alo[T][2], LO_SCALE_INV, ahi[T][2]);
                o.w = fmaf(alo[T][3], LO_SCALE_INV, ahi[T][3]);
                *(float4*)&out[(pbase + ptl) * 256 + ocb + T * 16 + g * 4] = o;
            }
        }
    }
}

// ---------------------------------------------------------------------------
// Single cooperative kernel: phase 1, grid sync, phase 2.
// 512 blocks x 256 thr; 32 KiB LDS (phase-2 mS aliases phase-1 hA/hB).
// ---------------------------------------------------------------------------
__global__ __launch_bounds__(256, 2) void k_fused(
    const float* __restrict__ x, const int* __restrict__ knn,
    const float* __restrict__ W1, const float* __restrict__ b1,
    const float* __restrict__ Wc0, const float* __restrict__ bc0,
    const float* __restrict__ Wc1, const float* __restrict__ bc1,
    const float* __restrict__ W2, const float* __restrict__ b2,
    _Float16* __restrict__ t, float* __restrict__ out)
{
    __shared__ __align__(16) _Float16 smem[16384];   // 32 KiB

    const int tid = threadIdx.x;
    const int bid = blockIdx.x;

    mlp_phase(bid, tid, smem, smem + 8192, x, W1, b1, Wc0, bc0, Wc1, bc1, t);

    __threadfence();
    cg::this_grid().sync();

    out_phase(bid, tid, smem, knn, t, W2, b2, out);
}

// Fallback pair (identical math) if cooperative launch is rejected.
__global__ __launch_bounds__(256) void k_mlp_fb(
    const float* __restrict__ x,
    const float* __restrict__ W1, const float* __restrict__ b1,
    const float* __restrict__ Wc0, const float* __restrict__ bc0,
    const float* __restrict__ Wc1, const float* __restrict__ bc1,
    _Float16* __restrict__ t)
{
    __shared__ __align__(16) _Float16 smem[16384];
    mlp_phase(blockIdx.x, threadIdx.x, smem, smem + 8192,
              x, W1, b1, Wc0, bc0, Wc1, bc1, t);
}

__global__ __launch_bounds__(256) void k_out_fb(
    const int* __restrict__ knn, const _Float16* __restrict__ t,
    const float* __restrict__ W2, const float* __restrict__ b2,
    float* __restrict__ out)
{
    __shared__ __align__(16) _Float16 smem[16384];
    out_phase(blockIdx.x, threadIdx.x, smem, knn, t, W2, b2, out);
}

// ---------------------------------------------------------------------------

extern "C" void kernel_launch(void* const* d_in, const int* in_sizes, int n_in,
                              void* d_out, int out_size, void* d_ws, size_t ws_size,
                              hipStream_t stream)
{
    const float* x   = (const float*)d_in[0];
    const int*   knn = (const int*)d_in[1];
    const float* W1  = (const float*)d_in[2];
    const float* b1  = (const float*)d_in[3];
    const float* Wc0 = (const float*)d_in[4];
    const float* bc0 = (const float*)d_in[5];
    const float* Wc1 = (const float*)d_in[6];
    const float* bc1 = (const float*)d_in[7];
    const float* W2  = (const float*)d_in[8];
    const float* b2  = (const float*)d_in[9];
    float* out = (float*)d_out;

    _Float16* t = (_Float16*)d_ws;   // 16 MiB

    void* args[] = {
        (void*)&x, (void*)&knn, (void*)&W1, (void*)&b1, (void*)&Wc0, (void*)&bc0,
        (void*)&Wc1, (void*)&bc1, (void*)&W2, (void*)&b2, (void*)&t, (void*)&out
    };
    const hipError_t e = hipLaunchCooperativeKernel(
        (const void*)k_fused, dim3(512), dim3(256), args, 0, stream);

    if (e != hipSuccess) {
        // same math, two dispatches (R4-proven path)
        k_mlp_fb<<<dim3(512), dim3(256), 0, stream>>>(x, W1, b1, Wc0, bc0, Wc1, bc1, t);
        k_out_fb<<<dim3(512), dim3(256), 0, stream>>>(knn, t, W2, b2, out);
    }
}

// Round 12
// 72.887 us; speedup vs baseline: 2.8371x; 2.8371x over previous
//
#include <hip/hip_runtime.h>

// AugmentShallow, round 12: re-anchor on R4 (best passing, 77us), with two
// zero-risk tweaks proven in other passing rounds:
//   1. k_out2 hoists the W2 half-0 fragment split ABOVE the gather phase so
//      its global-load latency hides under the gather's independent loads
//      (structure identical to R6, which passed with stable absmax).
//   2. Gather k-loop fully unrolled (12 independent row loads in flight).
// k_mlp is R4-verbatim. Math bit-identical to R4 -> absmax 9.766e-4.
//
// Pipeline: k_mlp (t[b,j] = MLP(x[b,j]), f16, hi/lo split GEMMs) ;
//           k_out2 (m = mean_12 gather(t) -> LDS -> out = W2 m + b2).
// ws: [0,16Mi) t f16 [65536][128].

typedef __attribute__((ext_vector_type(8))) _Float16 h8;
typedef __attribute__((ext_vector_type(4))) _Float16 h4;
typedef __attribute__((ext_vector_type(4))) float    f4;

#define MFMA_H __builtin_amdgcn_mfma_f32_16x16x32_f16

#define LO_SCALE_INV 2.44140625e-4f   // 2^-12

__device__ __forceinline__ void splitW8(const float* __restrict__ p, h8& hi, h8& lo) {
    const float4 a = *(const float4*)p;
    const float4 b = *(const float4*)(p + 4);
    const float v[8] = {a.x, a.y, a.z, a.w, b.x, b.y, b.z, b.w};
#pragma unroll
    for (int j = 0; j < 8; ++j) {
        const _Float16 h = (_Float16)v[j];
        hi[j] = h;
        lo[j] = (_Float16)((v[j] - (float)h) * 4096.f);
    }
}

// ---------------------------------------------------------------------------
// Kernel 1: point MLP (R4 verbatim). 1024 blocks x 256 thr, 64 pts/block.
// Wave w owns oc strip [32w, 32w+32); weights split in-register; h ping-pong
// in LDS with chunk^(pt&7) swizzle.
// ---------------------------------------------------------------------------
__global__ __launch_bounds__(256) void k_mlp(
    const float* __restrict__ x,
    const float* __restrict__ W1, const float* __restrict__ b1,
    const float* __restrict__ Wc0, const float* __restrict__ bc0,
    const float* __restrict__ Wc1, const float* __restrict__ bc1,
    _Float16* __restrict__ t)
{
    __shared__ __align__(16) _Float16 hA[64 * 128];   // 16 KiB
    __shared__ __align__(16) _Float16 hB[64 * 128];   // 16 KiB

    const int tid = threadIdx.x;
    const int bid = blockIdx.x;
    const int lb  = (bid & 7) * 128 + (bid >> 3);   // batch = lb>>7 = bid&7 (XCD pin)
    const long pblk = (long)lb * 64;

    // ---- layer 1 (VALU, K=3, no relu): thread = (pt, 32-ch quarter) ----
    {
        const int pt  = tid >> 2;
        const int q4  = tid & 3;
        const int ch0 = q4 * 32;
        const float* xp = x + (pblk + pt) * 3;
        const float x0 = xp[0], x1 = xp[1], x2 = xp[2];
        const int p7 = pt & 7;
#pragma unroll
        for (int q = 0; q < 4; ++q) {
            h8 hv;
#pragma unroll
            for (int j = 0; j < 8; ++j) {
                const int c = ch0 + q * 8 + j;
                float v = b1[c];
                v = fmaf(W1[c * 3 + 0], x0, v);
                v = fmaf(W1[c * 3 + 1], x1, v);
                v = fmaf(W1[c * 3 + 2], x2, v);
                hv[j] = (_Float16)v;
            }
            const int chunk = q4 * 4 + q;
            *(h8*)&hA[pt * 128 + ((chunk ^ p7) << 3)] = hv;
        }
    }
    __syncthreads();

    const int lane = tid & 63;
    const int w  = tid >> 6;
    const int fr = lane & 15;
    const int g  = lane >> 4;
    const int ocb = w * 32;

#pragma unroll
    for (int layer = 0; layer < 2; ++layer) {
        const float* W  = layer ? Wc1 : Wc0;
        const float* bp = layer ? bc1 : bc0;

        h8 Ah[2][4], Al[2][4];
#pragma unroll
        for (int T = 0; T < 2; ++T)
#pragma unroll
            for (int c = 0; c < 4; ++c)
                splitW8(W + (long)(ocb + T * 16 + fr) * 128 + c * 32 + g * 8,
                        Ah[T][c], Al[T][c]);

        f4 bias[2];
#pragma unroll
        for (int T = 0; T < 2; ++T) {
            const float4 bv = *(const float4*)(bp + ocb + T * 16 + g * 4);
            bias[T] = (f4){bv.x, bv.y, bv.z, bv.w};
        }

        const _Float16* hin = layer ? hB : hA;
        const f4 zf = {0.f, 0.f, 0.f, 0.f};

#pragma unroll 2
        for (int p = 0; p < 4; ++p) {
            const int pt = p * 16 + fr;
            const int p7 = pt & 7;
            h8 B[4];
#pragma unroll
            for (int c = 0; c < 4; ++c)
                B[c] = *(const h8*)&hin[pt * 128 + (((4 * c + g) ^ p7) << 3)];

            f4 ahi[2] = {bias[0], bias[1]};
            f4 alo[2] = {zf, zf};
#pragma unroll
            for (int c = 0; c < 4; ++c) {
#pragma unroll
                for (int T = 0; T < 2; ++T) {
                    ahi[T] = MFMA_H(Ah[T][c], B[c], ahi[T], 0, 0, 0);
                    alo[T] = MFMA_H(Al[T][c], B[c], alo[T], 0, 0, 0);
                }
            }
#pragma unroll
            for (int T = 0; T < 2; ++T) {
                const int ocoff = ocb + T * 16 + g * 4;
                h4 o;
#pragma unroll
                for (int r = 0; r < 4; ++r)
                    o[r] = (_Float16)fmaxf(fmaf(alo[T][r], LO_SCALE_INV, ahi[T][r]), 0.f);
                if (layer == 0) {
                    const int sidx = pt * 128 + (((ocoff >> 3) ^ p7) << 3) + (ocoff & 7);
                    *(h4*)&hB[sidx] = o;
                } else {
                    *(h4*)&t[(pblk + pt) * 128 + ocoff] = o;
                }
            }
        }
        if (layer == 0) __syncthreads();
    }
}

// ---------------------------------------------------------------------------
// Kernel 2 (R4 structure + W2-prefetch + full gather unroll):
// gather-mean -> LDS -> out = W2 m + b2. 512 blocks x 256 thr, 128 pts.
// ---------------------------------------------------------------------------
__global__ __launch_bounds__(256) void k_out2(
    const int* __restrict__ knn,
    const _Float16* __restrict__ t,
    const float* __restrict__ W2, const float* __restrict__ b2,
    float* __restrict__ out)
{
    __shared__ __align__(16) _Float16 mS[128 * 128];   // 32 KiB

    const int tid = threadIdx.x;
    const int bid = blockIdx.x;
    const int lb  = (bid & 7) * 64 + (bid >> 3);    // batch = lb>>6 = bid&7
    const long pbase = (long)lb * 128;
    const long bbase = (pbase >> 13) << 13;         // batch row base in t

    const int lane = tid & 63;
    const int w  = tid >> 6;
    const int fr = lane & 15;
    const int g  = lane >> 4;

    // ---- issue + split W2 half-0 fragments BEFORE the gather (latency
    //      hides under the gather's independent loads; R6-proven) ----
    h8 Ah[2][4], Al[2][4];
    {
        const int ocb0 = 0 * 128 + w * 32;
#pragma unroll
        for (int T = 0; T < 2; ++T)
#pragma unroll
            for (int c = 0; c < 4; ++c)
                splitW8(W2 + (long)(ocb0 + T * 16 + fr) * 128 + c * 32 + g * 8,
                        Ah[T][c], Al[T][c]);
    }

    // ---- gather-mean into LDS: 4 passes x 32 pts; thread=(pt, 8-ch oct) ----
    {
        const int oct = tid & 7;
        const int o8  = oct * 8;
#pragma unroll 1
        for (int pass = 0; pass < 4; ++pass) {
            const int ptl = pass * 32 + (tid >> 3);
            const int* ip = knn + (pbase + ptl) * 12;
            int idx[12];
            *(int4*)&idx[0] = *(const int4*)(ip + 0);
            *(int4*)&idx[4] = *(const int4*)(ip + 4);
            *(int4*)&idx[8] = *(const int4*)(ip + 8);

            float acc[16];
#pragma unroll
            for (int c = 0; c < 16; ++c) acc[c] = 0.f;
#pragma unroll
            for (int k = 0; k < 12; ++k) {
                const _Float16* tp = t + (bbase + idx[k]) * 128;
                const h8 va = *(const h8*)(tp + o8);
                const h8 vb = *(const h8*)(tp + 64 + o8);
#pragma unroll
                for (int j = 0; j < 8; ++j) acc[j] += (float)va[j];
#pragma unroll
                for (int j = 0; j < 8; ++j) acc[8 + j] += (float)vb[j];
            }
            h8 oa, ob;
#pragma unroll
            for (int j = 0; j < 8; ++j) {
                oa[j] = (_Float16)(acc[j] * (1.f / 12.f));
                ob[j] = (_Float16)(acc[8 + j] * (1.f / 12.f));
            }
            const int p7 = ptl & 7;
            *(h8*)&mS[ptl * 128 + ((oct ^ p7) << 3)]       = oa;
            *(h8*)&mS[ptl * 128 + (((oct + 8) ^ p7) << 3)] = ob;
        }
    }
    __syncthreads();

    // ---- GEMM: out = W2 m + b2, two 128-oc halves, plain stores ----
    const f4 zf = {0.f, 0.f, 0.f, 0.f};

#pragma unroll 1
    for (int half = 0; half < 2; ++half) {
        const int ocb = half * 128 + w * 32;
        if (half) {
#pragma unroll
            for (int T = 0; T < 2; ++T)
#pragma unroll
                for (int c = 0; c < 4; ++c)
                    splitW8(W2 + (long)(ocb + T * 16 + fr) * 128 + c * 32 + g * 8,
                            Ah[T][c], Al[T][c]);
        }

        f4 bias[2];
#pragma unroll
        for (int T = 0; T < 2; ++T) {
            const float4 bv = *(const float4*)(b2 + ocb + T * 16 + g * 4);
            bias[T] = (f4){bv.x, bv.y, bv.z, bv.w};
        }

#pragma unroll 2
        for (int p = 0; p < 8; ++p) {
            const int ptl = p * 16 + fr;
            const int p7  = ptl & 7;
            h8 B[4];
#pragma unroll
            for (int c = 0; c < 4; ++c)
                B[c] = *(const h8*)&mS[ptl * 128 + (((4 * c + g) ^ p7) << 3)];

            f4 ahi[2] = {bias[0], bias[1]};
            f4 alo[2] = {zf, zf};
#pragma unroll
            for (int c = 0; c < 4; ++c)
#pragma unroll
                for (int T = 0; T < 2; ++T) {
                    ahi[T] = MFMA_H(Ah[T][c], B[c], ahi[T], 0, 0, 0);
                    alo[T] = MFMA_H(Al[T][c], B[c], alo[T], 0, 0, 0);
                }
#pragma unroll
            for (int T = 0; T < 2; ++T) {
                float4 o;
                o.x = fmaf(alo[T][0], LO_SCALE_INV, ahi[T][0]);
                o.y = fmaf(alo[T][1], LO_SCALE_INV, ahi[T][1]);
                o.z = fmaf(alo[T][2], LO_SCALE_INV, ahi[T][2]);
                o.w = fmaf(alo[T][3], LO_SCALE_INV, ahi[T][3]);
                *(float4*)&out[(pbase + ptl) * 256 + ocb + T * 16 + g * 4] = o;
            }
        }
    }
}

// ---------------------------------------------------------------------------

extern "C" void kernel_launch(void* const* d_in, const int* in_sizes, int n_in,
                              void* d_out, int out_size, void* d_ws, size_t ws_size,
                              hipStream_t stream)
{
    const float* x   = (const float*)d_in[0];
    const int*   knn = (const int*)d_in[1];
    const float* W1  = (const float*)d_in[2];
    const float* b1  = (const float*)d_in[3];
    const float* Wc0 = (const float*)d_in[4];
    const float* bc0 = (const float*)d_in[5];
    const float* Wc1 = (const float*)d_in[6];
    const float* bc1 = (const float*)d_in[7];
    const float* W2  = (const float*)d_in[8];
    const float* b2  = (const float*)d_in[9];
    float* out = (float*)d_out;

    _Float16* t = (_Float16*)d_ws;   // 16 MiB

    k_mlp <<<dim3(1024), dim3(256), 0, stream>>>(x, W1, b1, Wc0, bc0, Wc1, bc1, t);
    k_out2<<<dim3(512),  dim3(256), 0, stream>>>(knn, t, W2, b2, out);
}

// Round 13
// 72.483 us; speedup vs baseline: 2.8529x; 1.0056x over previous
//
#include <hip/hip_runtime.h>

// AugmentShallow, round 13: R12 + k_out2 idx-preload (the one class of change
// that wins on this op: latency-hiding micro-reorderings in the R4 structure).
//
// k_out2 gather previously started each of 4 passes with a dependent idx
// load chain (~400-900 cyc serialized 4x). Now all 48 neighbor indices are
// loaded at kernel entry (in flight together with the W2 half-0 fragment
// loads), and the pass loop is FULLY UNROLLED so idx[][] indexing is
// compile-time-constant (rule: runtime-indexed reg arrays go to scratch) and
// the compiler can overlap pass p+1 loads with pass p converts.
// k_mlp is R12-verbatim. Math bit-identical -> absmax 9.766e-4.
//
// ws: [0,16Mi) t f16 [65536][128].

typedef __attribute__((ext_vector_type(8))) _Float16 h8;
typedef __attribute__((ext_vector_type(4))) _Float16 h4;
typedef __attribute__((ext_vector_type(4))) float    f4;

#define MFMA_H __builtin_amdgcn_mfma_f32_16x16x32_f16

#define LO_SCALE_INV 2.44140625e-4f   // 2^-12

__device__ __forceinline__ void splitW8(const float* __restrict__ p, h8& hi, h8& lo) {
    const float4 a = *(const float4*)p;
    const float4 b = *(const float4*)(p + 4);
    const float v[8] = {a.x, a.y, a.z, a.w, b.x, b.y, b.z, b.w};
#pragma unroll
    for (int j = 0; j < 8; ++j) {
        const _Float16 h = (_Float16)v[j];
        hi[j] = h;
        lo[j] = (_Float16)((v[j] - (float)h) * 4096.f);
    }
}

// ---------------------------------------------------------------------------
// Kernel 1: point MLP (R4/R12 verbatim). 1024 blocks x 256 thr, 64 pts/block.
// ---------------------------------------------------------------------------
__global__ __launch_bounds__(256) void k_mlp(
    const float* __restrict__ x,
    const float* __restrict__ W1, const float* __restrict__ b1,
    const float* __restrict__ Wc0, const float* __restrict__ bc0,
    const float* __restrict__ Wc1, const float* __restrict__ bc1,
    _Float16* __restrict__ t)
{
    __shared__ __align__(16) _Float16 hA[64 * 128];   // 16 KiB
    __shared__ __align__(16) _Float16 hB[64 * 128];   // 16 KiB

    const int tid = threadIdx.x;
    const int bid = blockIdx.x;
    const int lb  = (bid & 7) * 128 + (bid >> 3);   // batch = lb>>7 = bid&7 (XCD pin)
    const long pblk = (long)lb * 64;

    // ---- layer 1 (VALU, K=3, no relu): thread = (pt, 32-ch quarter) ----
    {
        const int pt  = tid >> 2;
        const int q4  = tid & 3;
        const int ch0 = q4 * 32;
        const float* xp = x + (pblk + pt) * 3;
        const float x0 = xp[0], x1 = xp[1], x2 = xp[2];
        const int p7 = pt & 7;
#pragma unroll
        for (int q = 0; q < 4; ++q) {
            h8 hv;
#pragma unroll
            for (int j = 0; j < 8; ++j) {
                const int c = ch0 + q * 8 + j;
                float v = b1[c];
                v = fmaf(W1[c * 3 + 0], x0, v);
                v = fmaf(W1[c * 3 + 1], x1, v);
                v = fmaf(W1[c * 3 + 2], x2, v);
                hv[j] = (_Float16)v;
            }
            const int chunk = q4 * 4 + q;
            *(h8*)&hA[pt * 128 + ((chunk ^ p7) << 3)] = hv;
        }
    }
    __syncthreads();

    const int lane = tid & 63;
    const int w  = tid >> 6;
    const int fr = lane & 15;
    const int g  = lane >> 4;
    const int ocb = w * 32;

#pragma unroll
    for (int layer = 0; layer < 2; ++layer) {
        const float* W  = layer ? Wc1 : Wc0;
        const float* bp = layer ? bc1 : bc0;

        h8 Ah[2][4], Al[2][4];
#pragma unroll
        for (int T = 0; T < 2; ++T)
#pragma unroll
            for (int c = 0; c < 4; ++c)
                splitW8(W + (long)(ocb + T * 16 + fr) * 128 + c * 32 + g * 8,
                        Ah[T][c], Al[T][c]);

        f4 bias[2];
#pragma unroll
        for (int T = 0; T < 2; ++T) {
            const float4 bv = *(const float4*)(bp + ocb + T * 16 + g * 4);
            bias[T] = (f4){bv.x, bv.y, bv.z, bv.w};
        }

        const _Float16* hin = layer ? hB : hA;
        const f4 zf = {0.f, 0.f, 0.f, 0.f};

#pragma unroll 2
        for (int p = 0; p < 4; ++p) {
            const int pt = p * 16 + fr;
            const int p7 = pt & 7;
            h8 B[4];
#pragma unroll
            for (int c = 0; c < 4; ++c)
                B[c] = *(const h8*)&hin[pt * 128 + (((4 * c + g) ^ p7) << 3)];

            f4 ahi[2] = {bias[0], bias[1]};
            f4 alo[2] = {zf, zf};
#pragma unroll
            for (int c = 0; c < 4; ++c) {
#pragma unroll
                for (int T = 0; T < 2; ++T) {
                    ahi[T] = MFMA_H(Ah[T][c], B[c], ahi[T], 0, 0, 0);
                    alo[T] = MFMA_H(Al[T][c], B[c], alo[T], 0, 0, 0);
                }
            }
#pragma unroll
            for (int T = 0; T < 2; ++T) {
                const int ocoff = ocb + T * 16 + g * 4;
                h4 o;
#pragma unroll
                for (int r = 0; r < 4; ++r)
                    o[r] = (_Float16)fmaxf(fmaf(alo[T][r], LO_SCALE_INV, ahi[T][r]), 0.f);
                if (layer == 0) {
                    const int sidx = pt * 128 + (((ocoff >> 3) ^ p7) << 3) + (ocoff & 7);
                    *(h4*)&hB[sidx] = o;
                } else {
                    *(h4*)&t[(pblk + pt) * 128 + ocoff] = o;
                }
            }
        }
        if (layer == 0) __syncthreads();
    }
}

// ---------------------------------------------------------------------------
// Kernel 2: gather-mean -> LDS -> out = W2 m + b2. 512 blocks x 256 thr,
// 128 pts/block. Entry order: issue ALL 48 idx loads, then W2 half-0 split
// (its loads overlap idx latency), then 4 fully-unrolled gather passes.
// ---------------------------------------------------------------------------
__global__ __launch_bounds__(256) void k_out2(
    const int* __restrict__ knn,
    const _Float16* __restrict__ t,
    const float* __restrict__ W2, const float* __restrict__ b2,
    float* __restrict__ out)
{
    __shared__ __align__(16) _Float16 mS[128 * 128];   // 32 KiB

    const int tid = threadIdx.x;
    const int bid = blockIdx.x;
    const int lb  = (bid & 7) * 64 + (bid >> 3);    // batch = lb>>6 = bid&7
    const long pbase = (long)lb * 128;
    const long bbase = (pbase >> 13) << 13;         // batch row base in t

    const int lane = tid & 63;
    const int w  = tid >> 6;
    const int fr = lane & 15;
    const int g  = lane >> 4;

    // ---- preload ALL neighbor indices (4 passes x 12), static indexing ----
    int idx[4][12];
    {
        const int ptb = tid >> 3;        // 0..31 within pass
#pragma unroll
        for (int pass = 0; pass < 4; ++pass) {
            const int* ip = knn + (pbase + pass * 32 + ptb) * 12;
            *(int4*)&idx[pass][0] = *(const int4*)(ip + 0);
            *(int4*)&idx[pass][4] = *(const int4*)(ip + 4);
            *(int4*)&idx[pass][8] = *(const int4*)(ip + 8);
        }
    }

    // ---- W2 half-0 fragment split (loads overlap idx latency) ----
    h8 Ah[2][4], Al[2][4];
    {
        const int ocb0 = w * 32;
#pragma unroll
        for (int T = 0; T < 2; ++T)
#pragma unroll
            for (int c = 0; c < 4; ++c)
                splitW8(W2 + (long)(ocb0 + T * 16 + fr) * 128 + c * 32 + g * 8,
                        Ah[T][c], Al[T][c]);
    }

    // ---- gather-mean into LDS: 4 fully-unrolled passes x 32 pts ----
    {
        const int oct = tid & 7;
        const int o8  = oct * 8;
        const int ptb = tid >> 3;
#pragma unroll
        for (int pass = 0; pass < 4; ++pass) {
            const int ptl = pass * 32 + ptb;

            float acc[16];
#pragma unroll
            for (int c = 0; c < 16; ++c) acc[c] = 0.f;
#pragma unroll
            for (int k = 0; k < 12; ++k) {
                const _Float16* tp = t + (bbase + idx[pass][k]) * 128;
                const h8 va = *(const h8*)(tp + o8);
                const h8 vb = *(const h8*)(tp + 64 + o8);
#pragma unroll
                for (int j = 0; j < 8; ++j) acc[j] += (float)va[j];
#pragma unroll
                for (int j = 0; j < 8; ++j) acc[8 + j] += (float)vb[j];
            }
            h8 oa, ob;
#pragma unroll
            for (int j = 0; j < 8; ++j) {
                oa[j] = (_Float16)(acc[j] * (1.f / 12.f));
                ob[j] = (_Float16)(acc[8 + j] * (1.f / 12.f));
            }
            const int p7 = ptl & 7;
            *(h8*)&mS[ptl * 128 + ((oct ^ p7) << 3)]       = oa;
            *(h8*)&mS[ptl * 128 + (((oct + 8) ^ p7) << 3)] = ob;
        }
    }
    __syncthreads();

    // ---- GEMM: out = W2 m + b2, two 128-oc halves, plain stores ----
    const f4 zf = {0.f, 0.f, 0.f, 0.f};

#pragma unroll 1
    for (int half = 0; half < 2; ++half) {
        const int ocb = half * 128 + w * 32;
        if (half) {
#pragma unroll
            for (int T = 0; T < 2; ++T)
#pragma unroll
                for (int c = 0; c < 4; ++c)
                    splitW8(W2 + (long)(ocb + T * 16 + fr) * 128 + c * 32 + g * 8,
                            Ah[T][c], Al[T][c]);
        }

        f4 bias[2];
#pragma unroll
        for (int T = 0; T < 2; ++T) {
            const float4 bv = *(const float4*)(b2 + ocb + T * 16 + g * 4);
            bias[T] = (f4){bv.x, bv.y, bv.z, bv.w};
        }

#pragma unroll 2
        for (int p = 0; p < 8; ++p) {
            const int ptl = p * 16 + fr;
            const int p7  = ptl & 7;
            h8 B[4];
#pragma unroll
            for (int c = 0; c < 4; ++c)
                B[c] = *(const h8*)&mS[ptl * 128 + (((4 * c + g) ^ p7) << 3)];

            f4 ahi[2] = {bias[0], bias[1]};
            f4 alo[2] = {zf, zf};
#pragma unroll
            for (int c = 0; c < 4; ++c)
#pragma unroll
                for (int T = 0; T < 2; ++T) {
                    ahi[T] = MFMA_H(Ah[T][c], B[c], ahi[T], 0, 0, 0);
                    alo[T] = MFMA_H(Al[T][c], B[c], alo[T], 0, 0, 0);
                }
#pragma unroll
            for (int T = 0; T < 2; ++T) {
                float4 o;
                o.x = fmaf(alo[T][0], LO_SCALE_INV, ahi[T][0]);
                o.y = fmaf(alo[T][1], LO_SCALE_INV, ahi[T][1]);
                o.z = fmaf(alo[T][2], LO_SCALE_INV, ahi[T][2]);
                o.w = fmaf(alo[T][3], LO_SCALE_INV, ahi[T][3]);
                *(float4*)&out[(pbase + ptl) * 256 + ocb + T * 16 + g * 4] = o;
            }
        }
    }
}

// ---------------------------------------------------------------------------

extern "C" void kernel_launch(void* const* d_in, const int* in_sizes, int n_in,
                              void* d_out, int out_size, void* d_ws, size_t ws_size,
                              hipStream_t stream)
{
    const float* x   = (const float*)d_in[0];
    const int*   knn = (const int*)d_in[1];
    const float* W1  = (const float*)d_in[2];
    const float* b1  = (const float*)d_in[3];
    const float* Wc0 = (const float*)d_in[4];
    const float* bc0 = (const float*)d_in[5];
    const float* Wc1 = (const float*)d_in[6];
    const float* bc1 = (const float*)d_in[7];
    const float* W2  = (const float*)d_in[8];
    const float* b2  = (const float*)d_in[9];
    float* out = (float*)d_out;

    _Float16* t = (_Float16*)d_ws;   // 16 MiB

    k_mlp <<<dim3(1024), dim3(256), 0, stream>>>(x, W1, b1, Wc0, bc0, Wc1, bc1, t);
    k_out2<<<dim3(512),  dim3(256), 0, stream>>>(knn, t, W2, b2, out);
}